// Round 17
// baseline (130.526 us; speedup 1.0000x reference)
//
#include <hip/hip_runtime.h>
#include <hip/hip_bf16.h>
#include <math.h>

typedef __bf16  bf16x8 __attribute__((ext_vector_type(8)));
typedef float   f32x4  __attribute__((ext_vector_type(4)));

// ---------------- helpers ----------------
static __device__ __forceinline__ void load_lds16(const void* g, void* l) {
  __builtin_amdgcn_global_load_lds(
      (const __attribute__((address_space(1))) void*)(g),
      (__attribute__((address_space(3))) void*)(l), 16, 0, 0);
}

#define BAR() asm volatile("s_barrier" ::: "memory")
#define SB0() __builtin_amdgcn_sched_barrier(0)
#define LGKM(N) do { asm volatile("s_waitcnt lgkmcnt(" #N ")" ::: "memory"); SB0(); } while (0)
#define VMC(N) asm volatile("s_waitcnt vmcnt(" #N ")" ::: "memory")

static __device__ __forceinline__ float bf2f(unsigned short u) {
  unsigned int x = ((unsigned int)u) << 16;
  return __builtin_bit_cast(float, x);
}
static __device__ __forceinline__ unsigned short f2bf(float f) {
  __hip_bfloat16 h = __float2bfloat16(f);
  return *reinterpret_cast<unsigned short*>(&h);
}
static __device__ __forceinline__ unsigned pack2bf(float lo, float hi) {
  return (unsigned)f2bf(lo) | ((unsigned)f2bf(hi) << 16);
}

// =====================================================================
// k_mid1: 1024 blocks: per-block t-table (reg+shfl) + gather/WHT_2048.
// Sw partials -> Sw_part[bid] (no atomic); reduced in k_mid2 block 0.
// (bias fastfood moved to k_mid2 block 256: mid1 runs at exactly 4
//  blocks/CU capacity, so a 1025th block was a serial tail.)
// =====================================================================
__global__ __launch_bounds__(256, 4) void k_mid1(
    const float* __restrict__ z, const float* __restrict__ BBw,
    const int* __restrict__ Piw, const float* __restrict__ GGw,
    float* __restrict__ Sw_part, __hip_bfloat16* __restrict__ m_buf) {
  __shared__ float S[4096];
  __shared__ float red[16];
  const int tid = threadIdx.x;
  const int bid = blockIdx.x;
  const int q6 = tid & 63, w = tid >> 6;

  // ------- t-table: t = WHT_2048(BBw*z) via reg+shfl butterfly -------
  {
    float v[8];
    float4 b0v = *reinterpret_cast<const float4*>(&BBw[tid * 8]);
    float4 b1v = *reinterpret_cast<const float4*>(&BBw[tid * 8 + 4]);
    float4 z0v = *reinterpret_cast<const float4*>(&z[tid * 8]);
    float4 z1v = *reinterpret_cast<const float4*>(&z[tid * 8 + 4]);
    v[0] = b0v.x * z0v.x; v[1] = b0v.y * z0v.y;
    v[2] = b0v.z * z0v.z; v[3] = b0v.w * z0v.w;
    v[4] = b1v.x * z1v.x; v[5] = b1v.y * z1v.y;
    v[6] = b1v.z * z1v.z; v[7] = b1v.w * z1v.w;
    #pragma unroll
    for (int st = 0; st < 3; ++st) {
      const int len = 1 << st;
      float t2[8];
      #pragma unroll
      for (int k = 0; k < 8; ++k) {
        int p = k ^ len;
        t2[k] = (k & len) ? v[p] - v[k] : v[k] + v[p];
      }
      #pragma unroll
      for (int k = 0; k < 8; ++k) v[k] = t2[k];
    }
    #pragma unroll
    for (int st = 0; st < 6; ++st) {
      const int xm = 1 << st;
      #pragma unroll
      for (int k = 0; k < 8; ++k) {
        float s2 = __shfl_xor(v[k], xm, 64);
        v[k] = (tid & xm) ? s2 - v[k] : v[k] + s2;
      }
    }
    #pragma unroll
    for (int k = 0; k < 8; ++k) S[2048 + k * 256 + tid] = v[k];
    __syncthreads();
    #pragma unroll
    for (int k = 0; k < 8; ++k) {
      float e0 = S[2048 + k * 256 + q6];
      float e1 = S[2048 + k * 256 + 64 + q6];
      float e2 = S[2048 + k * 256 + 128 + q6];
      float e3 = S[2048 + k * 256 + 192 + q6];
      float t1 = (w & 1) ? e0 - e1 : e0 + e1;
      float t2 = (w & 1) ? e2 - e3 : e2 + e3;
      v[k] = (w & 2) ? t1 - t2 : t1 + t2;
    }
    __syncthreads();
    f32x4 w0 = { v[0], v[1], v[2], v[3] };
    f32x4 w1 = { v[4], v[5], v[6], v[7] };
    *reinterpret_cast<f32x4*>(&S[tid * 8])     = w0;
    *reinterpret_cast<f32x4*>(&S[tid * 8 + 4]) = w1;
    __syncthreads();
  }

  // ---------------- gather + WHT_2048, 4 rows/block ----------------
  float ssum = 0.0f;
  for (int rr = 0; rr < 4; ++rr) {
    const size_t p0 = ((size_t)bid * 4 + rr) * 2048;
    float v[8];
    #pragma unroll
    for (int h = 0; h < 2; ++h) {
      int4   pv = *reinterpret_cast<const int4*>(&Piw[p0 + tid * 8 + h * 4]);
      float4 gv = *reinterpret_cast<const float4*>(&GGw[p0 + tid * 8 + h * 4]);
      v[h * 4 + 0] = S[pv.x & 2047] * gv.x;
      v[h * 4 + 1] = S[pv.y & 2047] * gv.y;
      v[h * 4 + 2] = S[pv.z & 2047] * gv.z;
      v[h * 4 + 3] = S[pv.w & 2047] * gv.w;
      ssum += gv.x * gv.x + gv.y * gv.y + gv.z * gv.z + gv.w * gv.w;
    }
    #pragma unroll
    for (int st = 0; st < 3; ++st) {
      const int len = 1 << st;
      float t2[8];
      #pragma unroll
      for (int k = 0; k < 8; ++k) {
        int p = k ^ len;
        t2[k] = (k & len) ? v[p] - v[k] : v[k] + v[p];
      }
      #pragma unroll
      for (int k = 0; k < 8; ++k) v[k] = t2[k];
    }
    #pragma unroll
    for (int st = 0; st < 6; ++st) {
      const int xm = 1 << st;
      #pragma unroll
      for (int k = 0; k < 8; ++k) {
        float s2 = __shfl_xor(v[k], xm, 64);
        v[k] = (tid & xm) ? s2 - v[k] : v[k] + s2;
      }
    }
    #pragma unroll
    for (int k = 0; k < 8; ++k) S[2048 + k * 256 + tid] = v[k];
    __syncthreads();
    #pragma unroll
    for (int k = 0; k < 8; ++k) {
      float e0 = S[2048 + k * 256 + q6];
      float e1 = S[2048 + k * 256 + 64 + q6];
      float e2 = S[2048 + k * 256 + 128 + q6];
      float e3 = S[2048 + k * 256 + 192 + q6];
      float t1 = (w & 1) ? e0 - e1 : e0 + e1;
      float t2 = (w & 1) ? e2 - e3 : e2 + e3;
      v[k] = (w & 2) ? t1 - t2 : t1 + t2;
    }
    ushort4 o0 = make_ushort4(f2bf(v[0]), f2bf(v[1]), f2bf(v[2]), f2bf(v[3]));
    ushort4 o1 = make_ushort4(f2bf(v[4]), f2bf(v[5]), f2bf(v[6]), f2bf(v[7]));
    *reinterpret_cast<ushort4*>(&m_buf[p0 + tid * 8])     = o0;
    *reinterpret_cast<ushort4*>(&m_buf[p0 + tid * 8 + 4]) = o1;
    __syncthreads();
  }
  for (int off = 32; off > 0; off >>= 1) ssum += __shfl_down(ssum, off);
  if ((tid & 63) == 0) red[w] = ssum;
  __syncthreads();
  if (tid == 0) Sw_part[bid] = red[0] + red[1] + red[2] + red[3];
}

// ---- k_mid2: xcast + WHT_64 o_lo (2 f-cols/thread) + Sw reduction;
//      block 256 = bias fastfood (hides under 256 BW-bound blocks) ----
__global__ __launch_bounds__(256, 2) void k_mid2(__hip_bfloat16* __restrict__ m_buf,
                                                 const float* __restrict__ x,
                                                 __hip_bfloat16* __restrict__ xb,
                                                 const float* __restrict__ Sw_part,
                                                 float* __restrict__ Sw,
                                                 const float* __restrict__ z,
                                                 const float* __restrict__ b0,
                                                 const float* __restrict__ BBb,
                                                 const float* __restrict__ GGb,
                                                 const int* __restrict__ Pib,
                                                 float* __restrict__ b_buf) {
  const int tid = threadIdx.x;
  if (blockIdx.x == 256) {
    // ---------------- bias fastfood (dedicated block) ----------------
    __shared__ float S[4096];
    __shared__ float red[16];
    for (int i = tid; i < 4096; i += 256)
      S[i] = (i < 2048) ? BBb[i] * z[i] : 0.0f;
    float s = 0.0f;
    for (int i = tid; i < 4096; i += 256) { float g = GGb[i]; s += g * g; }
    for (int off = 32; off > 0; off >>= 1) s += __shfl_down(s, off);
    if ((tid & 63) == 0) red[tid >> 6] = s;
    __syncthreads();
    for (int len = 1; len < 4096; len <<= 1) {
      #pragma unroll
      for (int q = 0; q < 8; ++q) {
        int j = q * 256 + tid;
        int a = ((j & ~(len - 1)) << 1) | (j & (len - 1));
        float xx = S[a], y = S[a + len];
        S[a] = xx + y; S[a + len] = xx - y;
      }
      __syncthreads();
    }
    float v[16];
    #pragma unroll
    for (int q = 0; q < 16; ++q) v[q] = S[Pib[q * 256 + tid]] * GGb[q * 256 + tid];
    __syncthreads();
    #pragma unroll
    for (int q = 0; q < 16; ++q) S[q * 256 + tid] = v[q];
    __syncthreads();
    for (int len = 1; len < 4096; len <<= 1) {
      #pragma unroll
      for (int q = 0; q < 8; ++q) {
        int j = q * 256 + tid;
        int a = ((j & ~(len - 1)) << 1) | (j & (len - 1));
        float xx = S[a], y = S[a + len];
        S[a] = xx + y; S[a + len] = xx - y;
      }
      __syncthreads();
    }
    float Sb = red[0] + red[1] + red[2] + red[3];
    const float scale = 1.0f / sqrtf(Sb * 4096.0f);
    for (int i = tid; i < 4096; i += 256) b_buf[i] = b0[i] + S[i] * scale;
    return;
  }

  const int gtid = blockIdx.x * 256 + tid;           // 0..65535
  // Sw reduction (block 0 only; visible to k_mid3 via kernel boundary)
  if (blockIdx.x == 0) {
    float s = 0.0f;
    for (int i = tid; i < 1024; i += 256) s += Sw_part[i];
    for (int off = 32; off > 0; off >>= 1) s += __shfl_down(s, off);
    __shared__ float r4[4];
    if ((tid & 63) == 0) r4[tid >> 6] = s;
    __syncthreads();
    if (tid == 0) *Sw = r4[0] + r4[1] + r4[2] + r4[3];
  }
  // xcast: 2^21 float4 quads over 65536 threads = 32 each
  #pragma unroll
  for (int i = 0; i < 32; ++i) {
    int q = gtid + i * 65536;
    float4 xv = reinterpret_cast<const float4*>(x)[q];
    ushort4 pk = make_ushort4(f2bf(xv.x), f2bf(xv.y), f2bf(xv.z), f2bf(xv.w));
    reinterpret_cast<ushort4*>(xb)[q] = pk;
  }
  // WHT_64 over o_lo: 2 f-columns per thread (uint = 2 bf16)
  const int f2 = gtid & 1023, oh = gtid >> 10;
  unsigned* mp = reinterpret_cast<unsigned*>(m_buf);
  const size_t base = (size_t)oh * 65536 + (size_t)f2;   // uint units
  float v0[64], v1[64];
  #pragma unroll
  for (int s = 0; s < 64; ++s) {
    unsigned u = mp[base + (size_t)s * 1024];
    v0[s] = bf2f((unsigned short)(u & 0xffff));
    v1[s] = bf2f((unsigned short)(u >> 16));
  }
  #pragma unroll
  for (int len = 1; len < 64; len <<= 1) {
    #pragma unroll
    for (int j = 0; j < 32; ++j) {
      int a = ((j & ~(len - 1)) << 1) | (j & (len - 1));
      float xx = v0[a], y = v0[a + len];
      v0[a] = xx + y; v0[a + len] = xx - y;
      float xx1 = v1[a], y1 = v1[a + len];
      v1[a] = xx1 + y1; v1[a + len] = xx1 - y1;
    }
  }
  #pragma unroll
  for (int s = 0; s < 64; ++s)
    mp[base + (size_t)s * 1024] = pack2bf(v0[s], v1[s]);
}

// ---- k_mid3: WHT_64 over o_hi + epilogue; 2 f-columns per thread ----
__global__ __launch_bounds__(256, 2) void k_mid3(const __hip_bfloat16* __restrict__ m_buf,
                                                 const float* __restrict__ W0,
                                                 const float* __restrict__ Sw,
                                                 __hip_bfloat16* __restrict__ Wb) {
  const int gtid = blockIdx.x * 256 + threadIdx.x;   // 0..65535
  const int f2 = gtid & 1023, ol = gtid >> 10;
  const unsigned* mp = reinterpret_cast<const unsigned*>(m_buf);
  const size_t baseu = (size_t)ol * 1024 + (size_t)f2;   // uint units; +s*65536
  float v0[64], v1[64];
  #pragma unroll
  for (int s = 0; s < 64; ++s) {
    unsigned u = mp[baseu + (size_t)s * 65536];
    v0[s] = bf2f((unsigned short)(u & 0xffff));
    v1[s] = bf2f((unsigned short)(u >> 16));
  }
  #pragma unroll
  for (int len = 1; len < 64; len <<= 1) {
    #pragma unroll
    for (int j = 0; j < 32; ++j) {
      int a = ((j & ~(len - 1)) << 1) | (j & (len - 1));
      float xx = v0[a], y = v0[a + len];
      v0[a] = xx + y; v0[a + len] = xx - y;
      float xx1 = v1[a], y1 = v1[a + len];
      v1[a] = xx1 + y1; v1[a + len] = xx1 - y1;
    }
  }
  const float scale = 1.0f / sqrtf((*Sw) * 8388608.0f);
  unsigned* wbu = reinterpret_cast<unsigned*>(Wb);
  #pragma unroll
  for (int s = 0; s < 64; ++s) {
    size_t eidx = ((size_t)ol * 2048 + (size_t)f2 * 2) + (size_t)s * 131072;
    float2 wv = *reinterpret_cast<const float2*>(&W0[eidx]);
    wbu[(eidx >> 1)] = pack2bf(wv.x + v0[s] * scale, wv.y + v1[s] * scale);
  }
}

// ---- GEMM: R5-exact schedule (frozen; 7 variants all 75-82us). ----
__global__ __launch_bounds__(512, 2) void k_gemm(const __hip_bfloat16* __restrict__ A,
                                                 const __hip_bfloat16* __restrict__ B,
                                                 const float* __restrict__ bias,
                                                 float* __restrict__ C) {
  constexpr int K = 2048, N = 4096, NT = K / 64;
  __shared__ __hip_bfloat16 As[2][256 * 64];
  __shared__ __hip_bfloat16 Bs[2][256 * 64];
  const int tid = threadIdx.x;
  const int wave = tid >> 6, lane = tid & 63;
  const int bid = blockIdx.x;
  const int row0 = (bid & 15) * 256;
  const int col0 = (bid >> 4) * 256;
  const int wr = wave >> 2, wc = wave & 3;
  const int srow = tid >> 3;
  const int gslot = (tid & 7) ^ (srow & 7);
  const int ldst = tid * 8;
  const int lr = lane & 15, lk = lane >> 4;

  f32x4 acc[8][4] = {};
  bf16x8 a0[4][2], a1[4][2], b0[2][2], b1[2][2];

  #define STAGE_A(BUF, KT, CH0)                                                 \
    { _Pragma("unroll") for (int c = 0; c < 2; ++c)                             \
        load_lds16(A + (size_t)(row0 + (CH0 + c) * 64 + srow) * K + (KT) * 64 + gslot * 8, \
                   &As[BUF][(CH0 + c) * 4096 + ldst]); }
  #define STAGE_B(BUF, KT, CH0)                                                 \
    { _Pragma("unroll") for (int c = 0; c < 2; ++c)                             \
        load_lds16(B + (size_t)(col0 + (CH0 + c) * 64 + srow) * K + (KT) * 64 + gslot * 8, \
                   &Bs[BUF][(CH0 + c) * 4096 + ldst]); }

  #define READ_A(DST, BUF, HALF)                                                \
    { _Pragma("unroll") for (int i = 0; i < 4; ++i)                             \
        _Pragma("unroll") for (int ks = 0; ks < 2; ++ks) {                      \
          int row = wr * 128 + (HALF) * 64 + i * 16 + lr;                       \
          DST[i][ks] = *(const bf16x8*)&As[BUF][row * 64 + (((ks * 4 + lk) ^ (row & 7)) * 8)]; } }
  #define READ_B(DST, BUF, HALF)                                                \
    { _Pragma("unroll") for (int j = 0; j < 2; ++j)                             \
        _Pragma("unroll") for (int ks = 0; ks < 2; ++ks) {                      \
          int row = wc * 64 + (HALF) * 32 + j * 16 + lr;                        \
          DST[j][ks] = *(const bf16x8*)&Bs[BUF][row * 64 + (((ks * 4 + lk) ^ (row & 7)) * 8)]; } }

  #define MFMA16(AF, BF, IO, JO)                                                \
    { __builtin_amdgcn_s_setprio(1);                                            \
      _Pragma("unroll") for (int i = 0; i < 4; ++i)                             \
        _Pragma("unroll") for (int j = 0; j < 2; ++j)                           \
          _Pragma("unroll") for (int ks = 0; ks < 2; ++ks)                      \
            acc[(IO) + i][(JO) + j] =                                           \
              __builtin_amdgcn_mfma_f32_16x16x32_bf16(AF[i][ks], BF[j][ks],     \
                                                      acc[(IO) + i][(JO) + j], 0, 0, 0); \
      __builtin_amdgcn_s_setprio(0); }

  // prologue: tile0 -> buf0, A(1)h0 -> buf1; drain ALL of tile0
  STAGE_A(0, 0, 0) STAGE_B(0, 0, 0) STAGE_A(0, 0, 2) STAGE_B(0, 0, 2)
  STAGE_A(1, 1, 0)
  VMC(2);
  BAR();

  for (int it = 0; it < 16; ++it) {
    const int u = 2 * it;
    const int v = u + 1;
    const int u2 = (u + 2 < NT) ? u + 2 : NT - 1;
    const int u3 = (u + 3 < NT) ? u + 3 : NT - 1;

    // ph1: reads a0,b0 (buf0); stage A(v)h1; gate VMC(4)
    READ_A(a0, 0, 0) READ_B(b0, 0, 0)
    STAGE_A(1, v, 2)
    LGKM(8);
    BAR(); LGKM(0);
    MFMA16(a0, b0, 0, 0)
    VMC(4);
    BAR();
    // ph2: reads b1 (buf0); stage B(v)h0
    READ_B(b1, 0, 1)
    STAGE_B(1, v, 0)
    BAR(); LGKM(0);
    MFMA16(a0, b1, 0, 2)
    BAR();
    // ph3: reads a1 (buf0); stage B(v)h1
    READ_A(a1, 0, 1)
    STAGE_B(1, v, 2)
    BAR(); LGKM(0);
    MFMA16(a1, b1, 4, 2)
    BAR();
    // ph4: stage A(u+2)h0 -> buf0; gate VMC(4)
    STAGE_A(0, u2, 0)
    BAR();
    MFMA16(a1, b0, 4, 0)
    VMC(4);
    BAR();

    // ph5: reads a0,b0 (buf1); stage B(u+2)h0 -> buf0; gate VMC(4)
    READ_A(a0, 1, 0) READ_B(b0, 1, 0)
    STAGE_B(0, u2, 0)
    LGKM(8);
    BAR(); LGKM(0);
    MFMA16(a0, b0, 0, 0)
    VMC(4);
    BAR();
    // ph6: reads b1 (buf1); stage A(u+2)h1 -> buf0
    READ_B(b1, 1, 1)
    STAGE_A(0, u2, 2)
    BAR(); LGKM(0);
    MFMA16(a0, b1, 0, 2)
    BAR();
    // ph7: reads a1 (buf1); stage B(u+2)h1 -> buf0
    READ_A(a1, 1, 1)
    STAGE_B(0, u2, 2)
    BAR(); LGKM(0);
    MFMA16(a1, b1, 4, 2)
    BAR();
    // ph8: stage A(u+3)h0 -> buf1; gate VMC(6)
    STAGE_A(1, u3, 0)
    BAR();
    MFMA16(a1, b0, 4, 0)
    VMC(6);
    BAR();
  }

  // epilogue: drain staging, LDS-staged coalesced C stores
  VMC(0);
  float bv[4];
  #pragma unroll
  for (int j = 0; j < 4; ++j) bv[j] = bias[col0 + wc * 64 + j * 16 + lr];
  float* eps = (float*)&As[0][0];
  #pragma unroll
  for (int r = 0; r < 4; ++r) {
    BAR();
    if (wr == (r >> 1)) {
      const int i0 = (r & 1) * 4;
      #pragma unroll
      for (int i = 0; i < 4; ++i)
        #pragma unroll
        for (int j = 0; j < 4; ++j)
          #pragma unroll
          for (int q = 0; q < 4; ++q) {
            int lrow = i * 16 + lk * 4 + q;
            int col = wc * 64 + j * 16 + lr;
            int sc = ((((col >> 2) ^ (lrow & 7)) << 2) | (col & 3));
            eps[lrow * 256 + sc] = acc[i0 + i][j][q] + bv[j];
          }
    }
    BAR();
    #pragma unroll
    for (int s = 0; s < 8; ++s) {
      int idx = s * 512 + tid;
      int lrow = idx >> 6;
      int g = idx & 63;
      f32x4 vv = *(const f32x4*)&eps[lrow * 256 + ((g ^ (lrow & 7)) << 2)];
      *(f32x4*)&C[(size_t)(row0 + r * 64 + lrow) * N + col0 + g * 4] = vv;
    }
  }
  #undef STAGE_A
  #undef STAGE_B
  #undef READ_A
  #undef READ_B
  #undef MFMA16
}

extern "C" void kernel_launch(void* const* d_in, const int* in_sizes, int n_in,
                              void* d_out, int out_size, void* d_ws, size_t ws_size,
                              hipStream_t stream) {
  (void)in_sizes; (void)n_in; (void)out_size; (void)ws_size;
  const float* x   = (const float*)d_in[0];
  const float* z   = (const float*)d_in[1];
  const float* W0  = (const float*)d_in[2];
  const float* b0  = (const float*)d_in[3];
  const float* BBw = (const float*)d_in[4];
  const float* GGw = (const float*)d_in[5];
  const float* BBb = (const float*)d_in[6];
  const float* GGb = (const float*)d_in[7];
  const int*   Piw = (const int*)d_in[8];
  const int*   Pib = (const int*)d_in[9];
  float* out = (float*)d_out;

  char* ws = (char*)d_ws;
  float*    b_buf   = (float*)(ws + 8192);        // 4096 f
  float*    Sw      = (float*)(ws + 24576);       // 1 f
  float*    Sw_part = (float*)(ws + 28672);       // 1024 f
  __hip_bfloat16* m_buf = (__hip_bfloat16*)(ws + 32768);                    // 16MB
  __hip_bfloat16* Wb = (__hip_bfloat16*)(ws + 32768 + 16777216);            // 16MB
  __hip_bfloat16* xb = (__hip_bfloat16*)(ws + 32768 + 16777216 + 16777216); // 16MB

  k_mid1<<<1024, 256, 0, stream>>>(z, BBw, Piw, GGw, Sw_part, m_buf);
  k_mid2<<<257, 256, 0, stream>>>(m_buf, x, xb, Sw_part, Sw,
                                  z, b0, BBb, GGb, Pib, b_buf);
  k_mid3<<<256, 256, 0, stream>>>(m_buf, W0, Sw, Wb);
  k_gemm<<<256, 512, 0, stream>>>(xb, Wb, b_buf, out);
}

// Round 18
// 126.988 us; speedup vs baseline: 1.0279x; 1.0279x over previous
//
#include <hip/hip_runtime.h>
#include <hip/hip_bf16.h>
#include <math.h>

typedef __bf16  bf16x8 __attribute__((ext_vector_type(8)));
typedef float   f32x4  __attribute__((ext_vector_type(4)));

// ---------------- helpers ----------------
static __device__ __forceinline__ void load_lds16(const void* g, void* l) {
  __builtin_amdgcn_global_load_lds(
      (const __attribute__((address_space(1))) void*)(g),
      (__attribute__((address_space(3))) void*)(l), 16, 0, 0);
}

#define BAR() asm volatile("s_barrier" ::: "memory")
#define SB0() __builtin_amdgcn_sched_barrier(0)
#define LGKM(N) do { asm volatile("s_waitcnt lgkmcnt(" #N ")" ::: "memory"); SB0(); } while (0)
#define VMC(N) asm volatile("s_waitcnt vmcnt(" #N ")" ::: "memory")

static __device__ __forceinline__ float bf2f(unsigned short u) {
  unsigned int x = ((unsigned int)u) << 16;
  return __builtin_bit_cast(float, x);
}
static __device__ __forceinline__ unsigned short f2bf(float f) {
  __hip_bfloat16 h = __float2bfloat16(f);
  return *reinterpret_cast<unsigned short*>(&h);
}
static __device__ __forceinline__ unsigned pack2bf(float lo, float hi) {
  return (unsigned)f2bf(lo) | ((unsigned)f2bf(hi) << 16);
}

// =====================================================================
// k_mid1: blocks 0..1023: per-block t-table (reg+shfl) + gather/WHT_2048
//         block 1024: bias fastfood only.
// Sw partials -> Sw_part[bid] (no atomic); reduced in k_mid2 block 0.
// =====================================================================
__global__ __launch_bounds__(256, 4) void k_mid1(
    const float* __restrict__ z, const float* __restrict__ BBw,
    const float* __restrict__ b0, const float* __restrict__ BBb,
    const float* __restrict__ GGb, const int* __restrict__ Pib,
    const int* __restrict__ Piw, const float* __restrict__ GGw,
    float* __restrict__ b_buf, float* __restrict__ Sw_part,
    __hip_bfloat16* __restrict__ m_buf) {
  __shared__ float S[4096];
  __shared__ float red[16];
  const int tid = threadIdx.x;
  const int bid = blockIdx.x;

  if (bid == 1024) {
    // ---------------- bias fastfood (dedicated block) ----------------
    for (int i = tid; i < 4096; i += 256)
      S[i] = (i < 2048) ? BBb[i] * z[i] : 0.0f;
    float s = 0.0f;
    for (int i = tid; i < 4096; i += 256) { float g = GGb[i]; s += g * g; }
    for (int off = 32; off > 0; off >>= 1) s += __shfl_down(s, off);
    if ((tid & 63) == 0) red[tid >> 6] = s;
    __syncthreads();
    for (int len = 1; len < 4096; len <<= 1) {
      #pragma unroll
      for (int q = 0; q < 8; ++q) {
        int j = q * 256 + tid;
        int a = ((j & ~(len - 1)) << 1) | (j & (len - 1));
        float xx = S[a], y = S[a + len];
        S[a] = xx + y; S[a + len] = xx - y;
      }
      __syncthreads();
    }
    float v[16];
    #pragma unroll
    for (int q = 0; q < 16; ++q) v[q] = S[Pib[q * 256 + tid]] * GGb[q * 256 + tid];
    __syncthreads();
    #pragma unroll
    for (int q = 0; q < 16; ++q) S[q * 256 + tid] = v[q];
    __syncthreads();
    for (int len = 1; len < 4096; len <<= 1) {
      #pragma unroll
      for (int q = 0; q < 8; ++q) {
        int j = q * 256 + tid;
        int a = ((j & ~(len - 1)) << 1) | (j & (len - 1));
        float xx = S[a], y = S[a + len];
        S[a] = xx + y; S[a + len] = xx - y;
      }
      __syncthreads();
    }
    float Sb = red[0] + red[1] + red[2] + red[3];
    const float scale = 1.0f / sqrtf(Sb * 4096.0f);
    for (int i = tid; i < 4096; i += 256) b_buf[i] = b0[i] + S[i] * scale;
    return;
  }

  const int q6 = tid & 63, w = tid >> 6;

  // ------- t-table: t = WHT_2048(BBw*z) via reg+shfl butterfly -------
  {
    float v[8];
    float4 b0v = *reinterpret_cast<const float4*>(&BBw[tid * 8]);
    float4 b1v = *reinterpret_cast<const float4*>(&BBw[tid * 8 + 4]);
    float4 z0v = *reinterpret_cast<const float4*>(&z[tid * 8]);
    float4 z1v = *reinterpret_cast<const float4*>(&z[tid * 8 + 4]);
    v[0] = b0v.x * z0v.x; v[1] = b0v.y * z0v.y;
    v[2] = b0v.z * z0v.z; v[3] = b0v.w * z0v.w;
    v[4] = b1v.x * z1v.x; v[5] = b1v.y * z1v.y;
    v[6] = b1v.z * z1v.z; v[7] = b1v.w * z1v.w;
    #pragma unroll
    for (int st = 0; st < 3; ++st) {
      const int len = 1 << st;
      float t2[8];
      #pragma unroll
      for (int k = 0; k < 8; ++k) {
        int p = k ^ len;
        t2[k] = (k & len) ? v[p] - v[k] : v[k] + v[p];
      }
      #pragma unroll
      for (int k = 0; k < 8; ++k) v[k] = t2[k];
    }
    #pragma unroll
    for (int st = 0; st < 6; ++st) {
      const int xm = 1 << st;
      #pragma unroll
      for (int k = 0; k < 8; ++k) {
        float s2 = __shfl_xor(v[k], xm, 64);
        v[k] = (tid & xm) ? s2 - v[k] : v[k] + s2;
      }
    }
    #pragma unroll
    for (int k = 0; k < 8; ++k) S[2048 + k * 256 + tid] = v[k];
    __syncthreads();
    #pragma unroll
    for (int k = 0; k < 8; ++k) {
      float e0 = S[2048 + k * 256 + q6];
      float e1 = S[2048 + k * 256 + 64 + q6];
      float e2 = S[2048 + k * 256 + 128 + q6];
      float e3 = S[2048 + k * 256 + 192 + q6];
      float t1 = (w & 1) ? e0 - e1 : e0 + e1;
      float t2 = (w & 1) ? e2 - e3 : e2 + e3;
      v[k] = (w & 2) ? t1 - t2 : t1 + t2;
    }
    __syncthreads();
    f32x4 w0 = { v[0], v[1], v[2], v[3] };
    f32x4 w1 = { v[4], v[5], v[6], v[7] };
    *reinterpret_cast<f32x4*>(&S[tid * 8])     = w0;
    *reinterpret_cast<f32x4*>(&S[tid * 8 + 4]) = w1;
    __syncthreads();
  }

  // ---------------- gather + WHT_2048, 4 rows/block ----------------
  float ssum = 0.0f;
  for (int rr = 0; rr < 4; ++rr) {
    const size_t p0 = ((size_t)bid * 4 + rr) * 2048;
    float v[8];
    #pragma unroll
    for (int h = 0; h < 2; ++h) {
      int4   pv = *reinterpret_cast<const int4*>(&Piw[p0 + tid * 8 + h * 4]);
      float4 gv = *reinterpret_cast<const float4*>(&GGw[p0 + tid * 8 + h * 4]);
      v[h * 4 + 0] = S[pv.x & 2047] * gv.x;
      v[h * 4 + 1] = S[pv.y & 2047] * gv.y;
      v[h * 4 + 2] = S[pv.z & 2047] * gv.z;
      v[h * 4 + 3] = S[pv.w & 2047] * gv.w;
      ssum += gv.x * gv.x + gv.y * gv.y + gv.z * gv.z + gv.w * gv.w;
    }
    #pragma unroll
    for (int st = 0; st < 3; ++st) {
      const int len = 1 << st;
      float t2[8];
      #pragma unroll
      for (int k = 0; k < 8; ++k) {
        int p = k ^ len;
        t2[k] = (k & len) ? v[p] - v[k] : v[k] + v[p];
      }
      #pragma unroll
      for (int k = 0; k < 8; ++k) v[k] = t2[k];
    }
    #pragma unroll
    for (int st = 0; st < 6; ++st) {
      const int xm = 1 << st;
      #pragma unroll
      for (int k = 0; k < 8; ++k) {
        float s2 = __shfl_xor(v[k], xm, 64);
        v[k] = (tid & xm) ? s2 - v[k] : v[k] + s2;
      }
    }
    #pragma unroll
    for (int k = 0; k < 8; ++k) S[2048 + k * 256 + tid] = v[k];
    __syncthreads();
    #pragma unroll
    for (int k = 0; k < 8; ++k) {
      float e0 = S[2048 + k * 256 + q6];
      float e1 = S[2048 + k * 256 + 64 + q6];
      float e2 = S[2048 + k * 256 + 128 + q6];
      float e3 = S[2048 + k * 256 + 192 + q6];
      float t1 = (w & 1) ? e0 - e1 : e0 + e1;
      float t2 = (w & 1) ? e2 - e3 : e2 + e3;
      v[k] = (w & 2) ? t1 - t2 : t1 + t2;
    }
    ushort4 o0 = make_ushort4(f2bf(v[0]), f2bf(v[1]), f2bf(v[2]), f2bf(v[3]));
    ushort4 o1 = make_ushort4(f2bf(v[4]), f2bf(v[5]), f2bf(v[6]), f2bf(v[7]));
    *reinterpret_cast<ushort4*>(&m_buf[p0 + tid * 8])     = o0;
    *reinterpret_cast<ushort4*>(&m_buf[p0 + tid * 8 + 4]) = o1;
    __syncthreads();
  }
  for (int off = 32; off > 0; off >>= 1) ssum += __shfl_down(ssum, off);
  if ((tid & 63) == 0) red[w] = ssum;
  __syncthreads();
  if (tid == 0) Sw_part[bid] = red[0] + red[1] + red[2] + red[3];
}

// ---- k_mid2: xcast + WHT_64 over o_lo (2 f-cols/thread) + Sw reduction ----
__global__ __launch_bounds__(256, 2) void k_mid2(__hip_bfloat16* __restrict__ m_buf,
                                                 const float* __restrict__ x,
                                                 __hip_bfloat16* __restrict__ xb,
                                                 const float* __restrict__ Sw_part,
                                                 float* __restrict__ Sw) {
  const int tid = threadIdx.x;
  const int gtid = blockIdx.x * 256 + tid;           // 0..65535
  // Sw reduction (block 0 only; visible to k_mid3 via kernel boundary)
  if (blockIdx.x == 0) {
    float s = 0.0f;
    for (int i = tid; i < 1024; i += 256) s += Sw_part[i];
    for (int off = 32; off > 0; off >>= 1) s += __shfl_down(s, off);
    __shared__ float r4[4];
    if ((tid & 63) == 0) r4[tid >> 6] = s;
    __syncthreads();
    if (tid == 0) *Sw = r4[0] + r4[1] + r4[2] + r4[3];
  }
  // xcast: 2^21 float4 quads over 65536 threads = 32 each
  #pragma unroll
  for (int i = 0; i < 32; ++i) {
    int q = gtid + i * 65536;
    float4 xv = reinterpret_cast<const float4*>(x)[q];
    ushort4 pk = make_ushort4(f2bf(xv.x), f2bf(xv.y), f2bf(xv.z), f2bf(xv.w));
    reinterpret_cast<ushort4*>(xb)[q] = pk;
  }
  // WHT_64 over o_lo: 2 f-columns per thread (uint = 2 bf16)
  const int f2 = gtid & 1023, oh = gtid >> 10;
  unsigned* mp = reinterpret_cast<unsigned*>(m_buf);
  const size_t base = (size_t)oh * 65536 + (size_t)f2;   // uint units
  float v0[64], v1[64];
  #pragma unroll
  for (int s = 0; s < 64; ++s) {
    unsigned u = mp[base + (size_t)s * 1024];
    v0[s] = bf2f((unsigned short)(u & 0xffff));
    v1[s] = bf2f((unsigned short)(u >> 16));
  }
  #pragma unroll
  for (int len = 1; len < 64; len <<= 1) {
    #pragma unroll
    for (int j = 0; j < 32; ++j) {
      int a = ((j & ~(len - 1)) << 1) | (j & (len - 1));
      float xx = v0[a], y = v0[a + len];
      v0[a] = xx + y; v0[a + len] = xx - y;
      float xx1 = v1[a], y1 = v1[a + len];
      v1[a] = xx1 + y1; v1[a + len] = xx1 - y1;
    }
  }
  #pragma unroll
  for (int s = 0; s < 64; ++s)
    mp[base + (size_t)s * 1024] = pack2bf(v0[s], v1[s]);
}

// ---- k_mid3: WHT_64 over o_hi + epilogue; 2 f-columns per thread ----
__global__ __launch_bounds__(256, 2) void k_mid3(const __hip_bfloat16* __restrict__ m_buf,
                                                 const float* __restrict__ W0,
                                                 const float* __restrict__ Sw,
                                                 __hip_bfloat16* __restrict__ Wb) {
  const int gtid = blockIdx.x * 256 + threadIdx.x;   // 0..65535
  const int f2 = gtid & 1023, ol = gtid >> 10;
  const unsigned* mp = reinterpret_cast<const unsigned*>(m_buf);
  const size_t baseu = (size_t)ol * 1024 + (size_t)f2;   // uint units; +s*65536
  float v0[64], v1[64];
  #pragma unroll
  for (int s = 0; s < 64; ++s) {
    unsigned u = mp[baseu + (size_t)s * 65536];
    v0[s] = bf2f((unsigned short)(u & 0xffff));
    v1[s] = bf2f((unsigned short)(u >> 16));
  }
  #pragma unroll
  for (int len = 1; len < 64; len <<= 1) {
    #pragma unroll
    for (int j = 0; j < 32; ++j) {
      int a = ((j & ~(len - 1)) << 1) | (j & (len - 1));
      float xx = v0[a], y = v0[a + len];
      v0[a] = xx + y; v0[a + len] = xx - y;
      float xx1 = v1[a], y1 = v1[a + len];
      v1[a] = xx1 + y1; v1[a + len] = xx1 - y1;
    }
  }
  const float scale = 1.0f / sqrtf((*Sw) * 8388608.0f);
  unsigned* wbu = reinterpret_cast<unsigned*>(Wb);
  #pragma unroll
  for (int s = 0; s < 64; ++s) {
    size_t eidx = ((size_t)ol * 2048 + (size_t)f2 * 2) + (size_t)s * 131072;
    float2 wv = *reinterpret_cast<const float2*>(&W0[eidx]);
    wbu[(eidx >> 1)] = pack2bf(wv.x + v0[s] * scale, wv.y + v1[s] * scale);
  }
}

// ---- GEMM: R5-exact schedule (frozen; 7 variants all 75-82us). ----
__global__ __launch_bounds__(512, 2) void k_gemm(const __hip_bfloat16* __restrict__ A,
                                                 const __hip_bfloat16* __restrict__ B,
                                                 const float* __restrict__ bias,
                                                 float* __restrict__ C) {
  constexpr int K = 2048, N = 4096, NT = K / 64;
  __shared__ __hip_bfloat16 As[2][256 * 64];
  __shared__ __hip_bfloat16 Bs[2][256 * 64];
  const int tid = threadIdx.x;
  const int wave = tid >> 6, lane = tid & 63;
  const int bid = blockIdx.x;
  const int row0 = (bid & 15) * 256;
  const int col0 = (bid >> 4) * 256;
  const int wr = wave >> 2, wc = wave & 3;
  const int srow = tid >> 3;
  const int gslot = (tid & 7) ^ (srow & 7);
  const int ldst = tid * 8;
  const int lr = lane & 15, lk = lane >> 4;

  f32x4 acc[8][4] = {};
  bf16x8 a0[4][2], a1[4][2], b0[2][2], b1[2][2];

  #define STAGE_A(BUF, KT, CH0)                                                 \
    { _Pragma("unroll") for (int c = 0; c < 2; ++c)                             \
        load_lds16(A + (size_t)(row0 + (CH0 + c) * 64 + srow) * K + (KT) * 64 + gslot * 8, \
                   &As[BUF][(CH0 + c) * 4096 + ldst]); }
  #define STAGE_B(BUF, KT, CH0)                                                 \
    { _Pragma("unroll") for (int c = 0; c < 2; ++c)                             \
        load_lds16(B + (size_t)(col0 + (CH0 + c) * 64 + srow) * K + (KT) * 64 + gslot * 8, \
                   &Bs[BUF][(CH0 + c) * 4096 + ldst]); }

  #define READ_A(DST, BUF, HALF)                                                \
    { _Pragma("unroll") for (int i = 0; i < 4; ++i)                             \
        _Pragma("unroll") for (int ks = 0; ks < 2; ++ks) {                      \
          int row = wr * 128 + (HALF) * 64 + i * 16 + lr;                       \
          DST[i][ks] = *(const bf16x8*)&As[BUF][row * 64 + (((ks * 4 + lk) ^ (row & 7)) * 8)]; } }
  #define READ_B(DST, BUF, HALF)                                                \
    { _Pragma("unroll") for (int j = 0; j < 2; ++j)                             \
        _Pragma("unroll") for (int ks = 0; ks < 2; ++ks) {                      \
          int row = wc * 64 + (HALF) * 32 + j * 16 + lr;                        \
          DST[j][ks] = *(const bf16x8*)&Bs[BUF][row * 64 + (((ks * 4 + lk) ^ (row & 7)) * 8)]; } }

  #define MFMA16(AF, BF, IO, JO)                                                \
    { __builtin_amdgcn_s_setprio(1);                                            \
      _Pragma("unroll") for (int i = 0; i < 4; ++i)                             \
        _Pragma("unroll") for (int j = 0; j < 2; ++j)                           \
          _Pragma("unroll") for (int ks = 0; ks < 2; ++ks)                      \
            acc[(IO) + i][(JO) + j] =                                           \
              __builtin_amdgcn_mfma_f32_16x16x32_bf16(AF[i][ks], BF[j][ks],     \
                                                      acc[(IO) + i][(JO) + j], 0, 0, 0); \
      __builtin_amdgcn_s_setprio(0); }

  // prologue: tile0 -> buf0, A(1)h0 -> buf1; drain ALL of tile0
  STAGE_A(0, 0, 0) STAGE_B(0, 0, 0) STAGE_A(0, 0, 2) STAGE_B(0, 0, 2)
  STAGE_A(1, 1, 0)
  VMC(2);
  BAR();

  for (int it = 0; it < 16; ++it) {
    const int u = 2 * it;
    const int v = u + 1;
    const int u2 = (u + 2 < NT) ? u + 2 : NT - 1;
    const int u3 = (u + 3 < NT) ? u + 3 : NT - 1;

    // ph1: reads a0,b0 (buf0); stage A(v)h1; gate VMC(4)
    READ_A(a0, 0, 0) READ_B(b0, 0, 0)
    STAGE_A(1, v, 2)
    LGKM(8);
    BAR(); LGKM(0);
    MFMA16(a0, b0, 0, 0)
    VMC(4);
    BAR();
    // ph2: reads b1 (buf0); stage B(v)h0
    READ_B(b1, 0, 1)
    STAGE_B(1, v, 0)
    BAR(); LGKM(0);
    MFMA16(a0, b1, 0, 2)
    BAR();
    // ph3: reads a1 (buf0); stage B(v)h1
    READ_A(a1, 0, 1)
    STAGE_B(1, v, 2)
    BAR(); LGKM(0);
    MFMA16(a1, b1, 4, 2)
    BAR();
    // ph4: stage A(u+2)h0 -> buf0; gate VMC(4)
    STAGE_A(0, u2, 0)
    BAR();
    MFMA16(a1, b0, 4, 0)
    VMC(4);
    BAR();

    // ph5: reads a0,b0 (buf1); stage B(u+2)h0 -> buf0; gate VMC(4)
    READ_A(a0, 1, 0) READ_B(b0, 1, 0)
    STAGE_B(0, u2, 0)
    LGKM(8);
    BAR(); LGKM(0);
    MFMA16(a0, b0, 0, 0)
    VMC(4);
    BAR();
    // ph6: reads b1 (buf1); stage A(u+2)h1 -> buf0
    READ_B(b1, 1, 1)
    STAGE_A(0, u2, 2)
    BAR(); LGKM(0);
    MFMA16(a0, b1, 0, 2)
    BAR();
    // ph7: reads a1 (buf1); stage B(u+2)h1 -> buf0
    READ_A(a1, 1, 1)
    STAGE_B(0, u2, 2)
    BAR(); LGKM(0);
    MFMA16(a1, b1, 4, 2)
    BAR();
    // ph8: stage A(u+3)h0 -> buf1; gate VMC(6)
    STAGE_A(1, u3, 0)
    BAR();
    MFMA16(a1, b0, 4, 0)
    VMC(6);
    BAR();
  }

  // epilogue: drain staging, LDS-staged coalesced C stores
  VMC(0);
  float bv[4];
  #pragma unroll
  for (int j = 0; j < 4; ++j) bv[j] = bias[col0 + wc * 64 + j * 16 + lr];
  float* eps = (float*)&As[0][0];
  #pragma unroll
  for (int r = 0; r < 4; ++r) {
    BAR();
    if (wr == (r >> 1)) {
      const int i0 = (r & 1) * 4;
      #pragma unroll
      for (int i = 0; i < 4; ++i)
        #pragma unroll
        for (int j = 0; j < 4; ++j)
          #pragma unroll
          for (int q = 0; q < 4; ++q) {
            int lrow = i * 16 + lk * 4 + q;
            int col = wc * 64 + j * 16 + lr;
            int sc = ((((col >> 2) ^ (lrow & 7)) << 2) | (col & 3));
            eps[lrow * 256 + sc] = acc[i0 + i][j][q] + bv[j];
          }
    }
    BAR();
    #pragma unroll
    for (int s = 0; s < 8; ++s) {
      int idx = s * 512 + tid;
      int lrow = idx >> 6;
      int g = idx & 63;
      f32x4 vv = *(const f32x4*)&eps[lrow * 256 + ((g ^ (lrow & 7)) << 2)];
      *(f32x4*)&C[(size_t)(row0 + r * 64 + lrow) * N + col0 + g * 4] = vv;
    }
  }
  #undef STAGE_A
  #undef STAGE_B
  #undef READ_A
  #undef READ_B
  #undef MFMA16
}

extern "C" void kernel_launch(void* const* d_in, const int* in_sizes, int n_in,
                              void* d_out, int out_size, void* d_ws, size_t ws_size,
                              hipStream_t stream) {
  (void)in_sizes; (void)n_in; (void)out_size; (void)ws_size;
  const float* x   = (const float*)d_in[0];
  const float* z   = (const float*)d_in[1];
  const float* W0  = (const float*)d_in[2];
  const float* b0  = (const float*)d_in[3];
  const float* BBw = (const float*)d_in[4];
  const float* GGw = (const float*)d_in[5];
  const float* BBb = (const float*)d_in[6];
  const float* GGb = (const float*)d_in[7];
  const int*   Piw = (const int*)d_in[8];
  const int*   Pib = (const int*)d_in[9];
  float* out = (float*)d_out;

  char* ws = (char*)d_ws;
  float*    b_buf   = (float*)(ws + 8192);        // 4096 f
  float*    Sw      = (float*)(ws + 24576);       // 1 f
  float*    Sw_part = (float*)(ws + 28672);       // 1024 f
  __hip_bfloat16* m_buf = (__hip_bfloat16*)(ws + 32768);                    // 16MB
  __hip_bfloat16* Wb = (__hip_bfloat16*)(ws + 32768 + 16777216);            // 16MB
  __hip_bfloat16* xb = (__hip_bfloat16*)(ws + 32768 + 16777216 + 16777216); // 16MB

  k_mid1<<<1025, 256, 0, stream>>>(z, BBw, b0, BBb, GGb, Pib, Piw, GGw,
                                   b_buf, Sw_part, m_buf);
  k_mid2<<<256, 256, 0, stream>>>(m_buf, x, xb, Sw_part, Sw);
  k_mid3<<<256, 256, 0, stream>>>(m_buf, W0, Sw, Wb);
  k_gemm<<<256, 512, 0, stream>>>(xb, Wb, b_buf, out);
}